// Round 3
// baseline (178.046 us; speedup 1.0000x reference)
//
#include <hip/hip_runtime.h>

#define BB 8
#define SS 4096
#define EE 256
#define CHUNKS 128
#define ROWS (SS / CHUNKS)   // 32 rows per block, 8 per wave

// Workspace layout (floats) — all partials deterministically written, no
// pre-zeroing needed (k2/k4 read only the ceil(len/ROWS) valid chunks):
//   sxp : [0,      262144)  per-chunk partial sums of x     [B][CHUNKS][E]
//   yp  : [262144, 524288)  per-chunk partial sums of w*x   [B][CHUNKS][E]
//   wp  : [524288, 525312)  per-chunk partial sums of w     [B][CHUNKS]
//   u   : [525312, 527360)  Wk^T @ sq                       [B][E]
//   c   : [527360, 527368)  sq . bk                         [B]
#define WS_SXP 0
#define WS_YP  (BB * CHUNKS * EE)
#define WS_WP  (2 * BB * CHUNKS * EE)
#define WS_U   (WS_WP + BB * CHUNKS)
#define WS_C   (WS_U + BB * EE)

// Pass 1: sxp[b][chunk][e] = sum over this chunk's valid rows of x[b,s,e]
__global__ __launch_bounds__(256) void k1_sumx(
    const float* __restrict__ x, const int* __restrict__ lengths,
    float* __restrict__ sxp)
{
    const int b = blockIdx.y, chunk = blockIdx.x;
    const int len = lengths[b];
    const int tid = threadIdx.x, wid = tid >> 6, lane = tid & 63;
    const int base = chunk * ROWS;
    if (base >= len) return;                  // block-uniform; k2 skips these
    const float4* xb = (const float4*)(x + (size_t)b * SS * EE);
    float4 acc = make_float4(0.f, 0.f, 0.f, 0.f);
    for (int r = wid; r < ROWS; r += 4) {
        const int row = base + r;             // wave-uniform predicate
        if (row < len) {
            float4 xv = xb[(size_t)row * (EE / 4) + lane];
            acc.x += xv.x; acc.y += xv.y; acc.z += xv.z; acc.w += xv.w;
        }
    }
    __shared__ float ysh[4][EE];
    ((float4*)ysh[wid])[lane] = acc;
    __syncthreads();
    float v = ysh[0][tid] + ysh[1][tid] + ysh[2][tid] + ysh[3][tid];
    sxp[((size_t)b * CHUNKS + chunk) * EE + tid] = v;
}

// Tiny per-batch: sx = sum valid chunk partials; sq = Wq sx + len*bq;
// u = Wk^T sq; c = sq . bk
__global__ __launch_bounds__(256) void k2_small(
    const float* __restrict__ Wq, const float* __restrict__ bq,
    const float* __restrict__ Wk, const float* __restrict__ bk,
    const int* __restrict__ lengths, const float* __restrict__ sxp,
    float* __restrict__ u, float* __restrict__ c)
{
    const int b = blockIdx.x, t = threadIdx.x;
    const int len = lengths[b];
    const int nch = (len + ROWS - 1) / ROWS;
    __shared__ float sxs[EE];
    __shared__ float sqs[EE];
    float s = 0.f;
    for (int ch = 0; ch < nch; ++ch)
        s += sxp[((size_t)b * CHUNKS + ch) * EE + t];   // coalesced across t
    sxs[t] = s;
    __syncthreads();
    const float lenf = (float)len;
    float acc = 0.f;
    const float* wrow = Wq + t * EE;
    #pragma unroll 8
    for (int e = 0; e < EE; ++e) acc += wrow[e] * sxs[e];
    sqs[t] = acc + lenf * bq[t];
    __syncthreads();
    float ua = 0.f;
    #pragma unroll 8
    for (int f = 0; f < EE; ++f) ua += Wk[f * EE + t] * sqs[f];  // coalesced
    u[b * EE + t] = ua;
    float p = sqs[t] * bk[t];
    #pragma unroll
    for (int m = 32; m; m >>= 1) p += __shfl_xor(p, m, 64);
    __shared__ float cred[4];
    if ((t & 63) == 0) cred[t >> 6] = p;
    __syncthreads();
    if (t == 0) c[b] = cred[0] + cred[1] + cred[2] + cred[3];
}

// Pass 2: w_s = u.x_s + c; yp[b][chunk] = sum w_s x_s; wp[b][chunk] = sum w_s
__global__ __launch_bounds__(256) void k3_main(
    const float* __restrict__ x, const int* __restrict__ lengths,
    const float* __restrict__ u, const float* __restrict__ c,
    float* __restrict__ yp, float* __restrict__ wp)
{
    const int b = blockIdx.y, chunk = blockIdx.x;
    const int len = lengths[b];
    const int tid = threadIdx.x, wid = tid >> 6, lane = tid & 63;
    const int base = chunk * ROWS;
    if (base >= len) return;                  // block-uniform; k4 skips these
    const float4 uv = ((const float4*)(u + b * EE))[lane];
    const float cb = c[b];
    const float4* xb = (const float4*)(x + (size_t)b * SS * EE);
    float4 yacc = make_float4(0.f, 0.f, 0.f, 0.f);
    float Wacc = 0.f;
    for (int r = wid; r < ROWS; r += 4) {
        const int row = base + r;             // wave-uniform predicate
        if (row < len) {
            float4 xv = xb[(size_t)row * (EE / 4) + lane];
            float p = uv.x * xv.x + uv.y * xv.y + uv.z * xv.z + uv.w * xv.w;
            #pragma unroll
            for (int m = 1; m < 64; m <<= 1) p += __shfl_xor(p, m, 64);
            p += cb;                          // w_s, broadcast to all lanes
            yacc.x += p * xv.x; yacc.y += p * xv.y;
            yacc.z += p * xv.z; yacc.w += p * xv.w;
            Wacc += p;
        }
    }
    __shared__ float ysh[4][EE];
    __shared__ float wsh[4];
    ((float4*)ysh[wid])[lane] = yacc;
    if (lane == 0) wsh[wid] = Wacc;
    __syncthreads();
    float v = ysh[0][tid] + ysh[1][tid] + ysh[2][tid] + ysh[3][tid];
    yp[((size_t)b * CHUNKS + chunk) * EE + tid] = v;
    if (tid == 0) wp[b * CHUNKS + chunk] = wsh[0] + wsh[1] + wsh[2] + wsh[3];
}

// Epilogue: y = sum valid yp chunks; W = sum valid wp chunks;
// out[b][f] = (Wv[f,:] . y + W*bv[f]) / S
__global__ __launch_bounds__(256) void k4_out(
    const float* __restrict__ Wv, const float* __restrict__ bv,
    const int* __restrict__ lengths, const float* __restrict__ yp,
    const float* __restrict__ wp, float* __restrict__ out)
{
    const int b = blockIdx.x, t = threadIdx.x;
    const int len = lengths[b];
    const int nch = (len + ROWS - 1) / ROWS;
    __shared__ float ysh[EE];
    float yv = 0.f;
    for (int ch = 0; ch < nch; ++ch)
        yv += yp[((size_t)b * CHUNKS + ch) * EE + t];   // coalesced across t
    ysh[t] = yv;
    // W reduction: one chunk per thread (CHUNKS=128 <= 256)
    float wv = (t < nch) ? wp[b * CHUNKS + t] : 0.f;
    #pragma unroll
    for (int m = 32; m; m >>= 1) wv += __shfl_xor(wv, m, 64);
    __shared__ float wred[4];
    if ((t & 63) == 0) wred[t >> 6] = wv;
    __syncthreads();
    const float Wb = wred[0] + wred[1] + wred[2] + wred[3];
    float acc = 0.f;
    const float* wrow = Wv + t * EE;
    #pragma unroll 8
    for (int e = 0; e < EE; ++e) acc += wrow[e] * ysh[e];
    out[b * EE + t] = (acc + Wb * bv[t]) * (1.0f / SS);
}

extern "C" void kernel_launch(void* const* d_in, const int* in_sizes, int n_in,
                              void* d_out, int out_size, void* d_ws, size_t ws_size,
                              hipStream_t stream) {
    const float* x  = (const float*)d_in[0];
    const float* Wq = (const float*)d_in[1];
    const float* bq = (const float*)d_in[2];
    const float* Wk = (const float*)d_in[3];
    const float* bk = (const float*)d_in[4];
    const float* Wv = (const float*)d_in[5];
    const float* bv = (const float*)d_in[6];
    const int* lengths = (const int*)d_in[7];
    float* out = (float*)d_out;
    float* ws = (float*)d_ws;

    float* sxp = ws + WS_SXP;
    float* yp  = ws + WS_YP;
    float* wp  = ws + WS_WP;
    float* u   = ws + WS_U;
    float* c   = ws + WS_C;

    dim3 grid1(CHUNKS, BB);
    k1_sumx<<<grid1, 256, 0, stream>>>(x, lengths, sxp);
    k2_small<<<BB, 256, 0, stream>>>(Wq, bq, Wk, bk, lengths, sxp, u, c);
    k3_main<<<grid1, 256, 0, stream>>>(x, lengths, u, c, yp, wp);
    k4_out<<<BB, 256, 0, stream>>>(Wv, bv, lengths, yp, wp, out);
}

// Round 4
// 167.241 us; speedup vs baseline: 1.0646x; 1.0646x over previous
//
#include <hip/hip_runtime.h>

#define BB 8
#define SS 4096
#define EE 256
#define CHUNKS 128
#define ROWS (SS / CHUNKS)   // 32 rows per block, 8 per wave

// Workspace layout (floats) — all partials deterministically written, no
// pre-zeroing needed:
//   sxp : [B][CHUNKS][E] per-chunk partial sums of x
//   yp  : [B][CHUNKS][E] per-chunk partial sums of w*x
//   wp  : [B][CHUNKS]    per-chunk partial sums of w
//   u,c : per-batch attention-collapse vectors
//   M   : Wk^T Wq  [E][E] (row-major, row t = output index)
//   g   : Wk^T bq  [E]
//   h   : Wq^T bk  [E]
//   d0  : bq . bk  [1]
#define WS_SXP 0
#define WS_YP  (BB * CHUNKS * EE)
#define WS_WP  (2 * BB * CHUNKS * EE)
#define WS_U   (WS_WP + BB * CHUNKS)
#define WS_C   (WS_U + BB * EE)
#define WS_M   (WS_C + BB)
#define WS_G   (WS_M + EE * EE)
#define WS_H   (WS_G + EE)
#define WS_D0  (WS_H + EE)

// Prep (x-independent): M = Wk^T Wq, g = Wk^T bq, h = Wq^T bk, d0 = bq.bk
__global__ __launch_bounds__(256) void kA_prep(
    const float* __restrict__ Wq, const float* __restrict__ bq,
    const float* __restrict__ Wk, const float* __restrict__ bk,
    float* __restrict__ M, float* __restrict__ g,
    float* __restrict__ h, float* __restrict__ d0)
{
    const int t = threadIdx.x, bid = blockIdx.x;
    if (bid < EE) {
        // M[row][e] = sum_f Wk[f][row] * Wq[f][e]; thread = e (coalesced Wq)
        const int row = bid;
        __shared__ float wkcol[EE];
        wkcol[t] = Wk[t * EE + row];     // column read, one load per thread
        __syncthreads();
        float acc = 0.f;
        #pragma unroll 8
        for (int f = 0; f < EE; ++f) acc += wkcol[f] * Wq[f * EE + t];
        M[row * EE + t] = acc;
    } else if (bid == EE) {
        // g[t] = sum_f Wk[f][t] * bq[f]  (coalesced across t)
        __shared__ float bqs[EE];
        bqs[t] = bq[t];
        __syncthreads();
        float acc = 0.f;
        #pragma unroll 8
        for (int f = 0; f < EE; ++f) acc += Wk[f * EE + t] * bqs[f];
        g[t] = acc;
    } else {
        // h[e] = sum_f Wq[f][e] * bk[f]  (coalesced across e); d0 = bq.bk
        __shared__ float bks[EE];
        __shared__ float bqs2[EE];
        bks[t] = bk[t];
        bqs2[t] = bq[t];
        __syncthreads();
        float acc = 0.f;
        #pragma unroll 8
        for (int f = 0; f < EE; ++f) acc += Wq[f * EE + t] * bks[f];
        h[t] = acc;
        float p = bqs2[t] * bks[t];
        #pragma unroll
        for (int m = 32; m; m >>= 1) p += __shfl_xor(p, m, 64);
        __shared__ float red[4];
        if ((t & 63) == 0) red[t >> 6] = p;
        __syncthreads();
        if (t == 0) d0[0] = red[0] + red[1] + red[2] + red[3];
    }
}

// Pass 1: sxp[b][chunk][e] = sum over this chunk's valid rows of x[b,s,e]
__global__ __launch_bounds__(256) void k1_sumx(
    const float* __restrict__ x, const int* __restrict__ lengths,
    float* __restrict__ sxp)
{
    const int b = blockIdx.y, chunk = blockIdx.x;
    const int len = lengths[b];
    const int tid = threadIdx.x, wid = tid >> 6, lane = tid & 63;
    const int base = chunk * ROWS;
    if (base >= len) return;                  // block-uniform; consumers skip
    const float4* xb = (const float4*)(x + (size_t)b * SS * EE);
    float4 acc = make_float4(0.f, 0.f, 0.f, 0.f);
    for (int r = wid; r < ROWS; r += 4) {
        const int row = base + r;             // wave-uniform predicate
        if (row < len) {
            float4 xv = xb[(size_t)row * (EE / 4) + lane];
            acc.x += xv.x; acc.y += xv.y; acc.z += xv.z; acc.w += xv.w;
        }
    }
    __shared__ float ysh[4][EE];
    ((float4*)ysh[wid])[lane] = acc;
    __syncthreads();
    float v = ysh[0][tid] + ysh[1][tid] + ysh[2][tid] + ysh[3][tid];
    sxp[((size_t)b * CHUNKS + chunk) * EE + tid] = v;
}

// Per-batch: sx = sum valid sxp chunks; u = M sx + len*g; c = h.sx + len*d0
// grid(8 tgroups, B); wave-per-output (coalesced float4 row reads)
__global__ __launch_bounds__(256) void kB_uc(
    const int* __restrict__ lengths, const float* __restrict__ sxp,
    const float* __restrict__ M, const float* __restrict__ g,
    const float* __restrict__ h, const float* __restrict__ d0,
    float* __restrict__ u, float* __restrict__ c)
{
    const int b = blockIdx.y, tg = blockIdx.x;
    const int tid = threadIdx.x, wid = tid >> 6, lane = tid & 63;
    const int len = lengths[b];
    const int nch = (len + ROWS - 1) / ROWS;
    __shared__ float sxs[EE];
    float s = 0.f;
    for (int ch = 0; ch < nch; ++ch)
        s += sxp[((size_t)b * CHUNKS + ch) * EE + tid];   // coalesced
    sxs[tid] = s;
    __syncthreads();
    const float lenf = (float)len;
    const float4 sxv = ((const float4*)sxs)[lane];
    #pragma unroll
    for (int j = 0; j < 8; ++j) {
        const int t = tg * 32 + wid * 8 + j;
        const float4 mr = ((const float4*)(M + t * EE))[lane];  // 1KB row/wave
        float p = mr.x * sxv.x + mr.y * sxv.y + mr.z * sxv.z + mr.w * sxv.w;
        #pragma unroll
        for (int m = 1; m < 64; m <<= 1) p += __shfl_xor(p, m, 64);
        if (lane == 0) u[b * EE + t] = p + lenf * g[t];
    }
    if (tg == 0) {
        float p = h[tid] * sxs[tid];
        #pragma unroll
        for (int m = 32; m; m >>= 1) p += __shfl_xor(p, m, 64);
        __shared__ float red[4];
        if ((tid & 63) == 0) red[tid >> 6] = p;
        __syncthreads();
        if (tid == 0) c[b] = red[0] + red[1] + red[2] + red[3] + lenf * d0[0];
    }
}

// Pass 2: w_s = u.x_s + c; yp[b][chunk] = sum w_s x_s; wp[b][chunk] = sum w_s
__global__ __launch_bounds__(256) void k3_main(
    const float* __restrict__ x, const int* __restrict__ lengths,
    const float* __restrict__ u, const float* __restrict__ c,
    float* __restrict__ yp, float* __restrict__ wp)
{
    const int b = blockIdx.y, chunk = blockIdx.x;
    const int len = lengths[b];
    const int tid = threadIdx.x, wid = tid >> 6, lane = tid & 63;
    const int base = chunk * ROWS;
    if (base >= len) return;                  // block-uniform; consumers skip
    const float4 uv = ((const float4*)(u + b * EE))[lane];
    const float cb = c[b];
    const float4* xb = (const float4*)(x + (size_t)b * SS * EE);
    float4 yacc = make_float4(0.f, 0.f, 0.f, 0.f);
    float Wacc = 0.f;
    for (int r = wid; r < ROWS; r += 4) {
        const int row = base + r;             // wave-uniform predicate
        if (row < len) {
            float4 xv = xb[(size_t)row * (EE / 4) + lane];
            float p = uv.x * xv.x + uv.y * xv.y + uv.z * xv.z + uv.w * xv.w;
            #pragma unroll
            for (int m = 1; m < 64; m <<= 1) p += __shfl_xor(p, m, 64);
            p += cb;                          // w_s, broadcast to all lanes
            yacc.x += p * xv.x; yacc.y += p * xv.y;
            yacc.z += p * xv.z; yacc.w += p * xv.w;
            Wacc += p;
        }
    }
    __shared__ float ysh[4][EE];
    __shared__ float wsh[4];
    ((float4*)ysh[wid])[lane] = yacc;
    if (lane == 0) wsh[wid] = Wacc;
    __syncthreads();
    float v = ysh[0][tid] + ysh[1][tid] + ysh[2][tid] + ysh[3][tid];
    yp[((size_t)b * CHUNKS + chunk) * EE + tid] = v;
    if (tid == 0) wp[b * CHUNKS + chunk] = wsh[0] + wsh[1] + wsh[2] + wsh[3];
}

// Epilogue: y = sum valid yp chunks; W = sum valid wp; out = (Wv y + W bv)/S
// grid(8 ogroups, B); wave-per-output (coalesced float4 Wv row reads)
__global__ __launch_bounds__(256) void k4_out(
    const float* __restrict__ Wv, const float* __restrict__ bv,
    const int* __restrict__ lengths, const float* __restrict__ yp,
    const float* __restrict__ wp, float* __restrict__ out)
{
    const int b = blockIdx.y, og = blockIdx.x;
    const int tid = threadIdx.x, wid = tid >> 6, lane = tid & 63;
    const int len = lengths[b];
    const int nch = (len + ROWS - 1) / ROWS;
    __shared__ float ysh[EE];
    float yv = 0.f;
    for (int ch = 0; ch < nch; ++ch)
        yv += yp[((size_t)b * CHUNKS + ch) * EE + tid];   // coalesced
    ysh[tid] = yv;
    float wv = (tid < nch) ? wp[b * CHUNKS + tid] : 0.f;  // CHUNKS<=256
    #pragma unroll
    for (int m = 32; m; m >>= 1) wv += __shfl_xor(wv, m, 64);
    __shared__ float wred[4];
    if ((tid & 63) == 0) wred[tid >> 6] = wv;
    __syncthreads();
    const float Wb = wred[0] + wred[1] + wred[2] + wred[3];
    const float4 yv4 = ((const float4*)ysh)[lane];
    #pragma unroll
    for (int j = 0; j < 8; ++j) {
        const int f = og * 32 + wid * 8 + j;
        const float4 wr = ((const float4*)(Wv + f * EE))[lane]; // 1KB row/wave
        float p = wr.x * yv4.x + wr.y * yv4.y + wr.z * yv4.z + wr.w * yv4.w;
        #pragma unroll
        for (int m = 1; m < 64; m <<= 1) p += __shfl_xor(p, m, 64);
        if (lane == 0) out[b * EE + f] = (p + Wb * bv[f]) * (1.0f / SS);
    }
}

extern "C" void kernel_launch(void* const* d_in, const int* in_sizes, int n_in,
                              void* d_out, int out_size, void* d_ws, size_t ws_size,
                              hipStream_t stream) {
    const float* x  = (const float*)d_in[0];
    const float* Wq = (const float*)d_in[1];
    const float* bq = (const float*)d_in[2];
    const float* Wk = (const float*)d_in[3];
    const float* bk = (const float*)d_in[4];
    const float* Wv = (const float*)d_in[5];
    const float* bv = (const float*)d_in[6];
    const int* lengths = (const int*)d_in[7];
    float* out = (float*)d_out;
    float* ws = (float*)d_ws;

    float* sxp = ws + WS_SXP;
    float* yp  = ws + WS_YP;
    float* wp  = ws + WS_WP;
    float* u   = ws + WS_U;
    float* c   = ws + WS_C;
    float* M   = ws + WS_M;
    float* g   = ws + WS_G;
    float* h   = ws + WS_H;
    float* d0  = ws + WS_D0;

    dim3 grid1(CHUNKS, BB);
    kA_prep<<<EE + 2, 256, 0, stream>>>(Wq, bq, Wk, bk, M, g, h, d0);
    k1_sumx<<<grid1, 256, 0, stream>>>(x, lengths, sxp);
    kB_uc<<<dim3(8, BB), 256, 0, stream>>>(lengths, sxp, M, g, h, d0, u, c);
    k3_main<<<grid1, 256, 0, stream>>>(x, lengths, u, c, yp, wp);
    k4_out<<<dim3(8, BB), 256, 0, stream>>>(Wv, bv, lengths, yp, wp, out);
}